// Round 3
// baseline (419.690 us; speedup 1.0000x reference)
//
#include <hip/hip_runtime.h>
#include <hip/hip_bf16.h>
#include <math.h>

// MOE: out[b,o] = sum_n gelu(x@gw^T+gb)[b,n] * (x @ W_n^T)[b,o]
// B=4096, N=32, IDIM=ODIM=1024.
// R3: 8-phase-style counted-vmcnt schedule (T3+T4+T5), BM=256 BN=128 BK=64,
// 8 waves, triple-buffered LDS (prefetch distance 2, vmcnt(6) never 0 in loop),
// per-expert fold from LDS-resident gate values, split-K x2 atomics.

#define BSZ  4096
#define NEXP 32
#define IDIM 1024
#define ODIM 1024

typedef __attribute__((ext_vector_type(8))) short bf16x8;
typedef __attribute__((ext_vector_type(4))) float f32x4;

#define GLOAD_LDS16(g, l) __builtin_amdgcn_global_load_lds( \
    (const __attribute__((address_space(1))) void*)(g),     \
    (__attribute__((address_space(3))) void*)(l), 16, 0, 0)

#define WAITV6 asm volatile("s_waitcnt vmcnt(6)" ::: "memory")
#define WAITV0 asm volatile("s_waitcnt vmcnt(0)" ::: "memory")
#define WAITL0 do { asm volatile("s_waitcnt lgkmcnt(0)" ::: "memory"); \
                    __builtin_amdgcn_sched_barrier(0); } while (0)
#define BARRIER do { __builtin_amdgcn_s_barrier(); \
                     __builtin_amdgcn_sched_barrier(0); } while (0)

__device__ __forceinline__ unsigned short f2bf(float f) {
  unsigned u = __float_as_uint(f);
  unsigned r = (u + 0x7FFFu + ((u >> 16) & 1u)) >> 16;  // RNE
  return (unsigned short)r;
}

// ---------------- zero d_out ----------------
__global__ void zero_kernel(float* __restrict__ out) {
  int i = blockIdx.x * blockDim.x + threadIdx.x;
  ((float4*)out)[i] = make_float4(0.f, 0.f, 0.f, 0.f);
}

// ---------------- fp32 -> bf16 conversion (8 elems/thread) ----------------
__global__ void conv_kernel(const float* __restrict__ in, unsigned short* __restrict__ outb) {
  int i = blockIdx.x * blockDim.x + threadIdx.x;
  const float4* p = (const float4*)in + (size_t)i * 2;
  float4 a = p[0], b = p[1];
  union { bf16x8 v; unsigned short s[8]; } o;
  o.s[0] = f2bf(a.x); o.s[1] = f2bf(a.y); o.s[2] = f2bf(a.z); o.s[3] = f2bf(a.w);
  o.s[4] = f2bf(b.x); o.s[5] = f2bf(b.y); o.s[6] = f2bf(b.z); o.s[7] = f2bf(b.w);
  ((bf16x8*)outb)[i] = o.v;
}

// ---------------- gate: gT[n][b] = gelu(x[b]·gw[n] + gb[n]) ----------------
__global__ void gate_kernel(const float* __restrict__ x, const float* __restrict__ gw,
                            const float* __restrict__ gb, float* __restrict__ gT) {
  const int lane = threadIdx.x & 63;
  const int row = blockIdx.x * 4 + (threadIdx.x >> 6);
  const float4* xr = (const float4*)(x + (size_t)row * IDIM);
  float4 xv[4];
#pragma unroll
  for (int t = 0; t < 4; ++t) xv[t] = xr[t * 64 + lane];
  for (int n = 0; n < NEXP; ++n) {
    const float4* wr = (const float4*)(gw + (size_t)n * IDIM);
    float s = 0.f;
#pragma unroll
    for (int t = 0; t < 4; ++t) {
      float4 wv = wr[t * 64 + lane];
      s += xv[t].x * wv.x + xv[t].y * wv.y + xv[t].z * wv.z + xv[t].w * wv.w;
    }
#pragma unroll
    for (int off = 32; off > 0; off >>= 1) s += __shfl_down(s, off, 64);
    if (lane == 0) {
      float v = s + gb[n];
      gT[(size_t)n * BSZ + row] = 0.5f * v * (1.0f + erff(v * 0.70710678118f));
    }
  }
}

// ---------------- main GEMM ----------------
// 256 blocks (1/CU), 512 threads (8 waves: 4M x 2N), per-wave 64x64 output.
// K per block = 16 experts * 1024 = 256 K-tiles of BK=64.
// Triple-buffered LDS; STAGE(kt+2) issued at kt; vmcnt(6) waits tile kt only.
// Per K-tile: 2 phases x {ds_read, lgkmcnt(0), setprio, 16 MFMA}.
__global__ __launch_bounds__(512, 2) void gemm_kernel(
    const unsigned short* __restrict__ xb,   // [4096][1024] bf16
    const unsigned short* __restrict__ wb,   // [32][1024][1024] bf16 (n,o,i)
    const float* __restrict__ gT,            // [32][4096]
    float* __restrict__ out)                 // [4096][1024] fp32
{
  __shared__ unsigned short As[3][256 * 64];   // 96 KB
  __shared__ unsigned short Bs[3][128 * 64];   // 48 KB
  __shared__ float g_lds[16][256];             // 16 KB  (total 160 KiB exact)

  const int tid  = threadIdx.x;
  const int lane = tid & 63;
  const int wid  = tid >> 6;     // 0..7
  const int wm   = wid >> 1;     // 0..3 (M)
  const int wn   = wid & 1;      // 0..1 (N)

  // XCD-chunked block swizzle: 256 % 8 == 0 -> bijective
  const int orig  = blockIdx.x;
  const int wgid  = (orig & 7) * 32 + (orig >> 3);
  const int mtile = wgid & 15;          // innermost: 16 blocks share W panel
  const int grp   = wgid >> 4;          // 0..15
  const int split = grp & 1;
  const int col0  = (grp >> 1) * 128;
  const int row0  = mtile * 256;

  // staging: lane -> (row-in-chunk, pre-swizzled source granule)
  const int srow = lane >> 3;
  const int jsrc = (lane & 7) ^ srow;
  size_t a_off[4], b_off[2];
#pragma unroll
  for (int l = 0; l < 4; ++l)
    a_off[l] = (size_t)(row0 + (wid * 4 + l) * 8 + srow) * IDIM + jsrc * 8;
#pragma unroll
  for (int l = 0; l < 2; ++l)
    b_off[l] = (size_t)(col0 + (wid * 2 + l) * 8 + srow) * IDIM + jsrc * 8;

  const int frow = lane & 15;
  const int hi   = lane >> 4;

  f32x4 acc[4][4], acc_e[4][4];
#pragma unroll
  for (int i = 0; i < 4; ++i)
#pragma unroll
    for (int j = 0; j < 4; ++j) {
      acc[i][j]   = f32x4{0.f, 0.f, 0.f, 0.f};
      acc_e[i][j] = f32x4{0.f, 0.f, 0.f, 0.f};
    }

  // gate slice -> LDS (16 experts x 256 rows)
  {
    const int e = tid >> 5;
    const int r = (tid & 31) * 8;
    const float* src = gT + ((size_t)(split * 16 + e) << 12) + row0 + r;
    *(float4*)&g_lds[e][r]     = *(const float4*)src;
    *(float4*)&g_lds[e][r + 4] = *(const float4*)(src + 4);
  }

  auto STAGE = [&](int buf, int kt) {
    const int e  = kt >> 4;
    const int i0 = (kt & 15) << 6;
    const unsigned short* wb_n = wb + ((size_t)(split * 16 + e) << 20);
#pragma unroll
    for (int l = 0; l < 4; ++l)
      GLOAD_LDS16(xb + a_off[l] + i0, &As[buf][(wid * 4 + l) * 512]);
#pragma unroll
    for (int l = 0; l < 2; ++l)
      GLOAD_LDS16(wb_n + b_off[l] + i0, &Bs[buf][(wid * 2 + l) * 512]);
  };

  __syncthreads();         // g_lds visible to all waves; full drain (prologue only)
  STAGE(0, 0);             // 6 loads
  STAGE(1, 1);             // 12 outstanding

  int cur = 0;
#pragma unroll 1
  for (int kt = 0; kt < 256; ++kt) {
    // wait for tile kt's own 6 loads (oldest of 12), then rendezvous:
    // after the barrier, EVERY wave's tile-kt loads are complete.
    if (kt == 255) { WAITV0; } else { WAITV6; }
    BARRIER;
    // prefetch tile kt+2 into the buffer freed at the barrier ((kt-1)%3)
    if (kt < 254) { int s = cur + 2; if (s >= 3) s -= 3; STAGE(s, kt + 2); }

    const unsigned short* A_ = &As[cur][0];
    const unsigned short* B_ = &Bs[cur][0];

    // ---- phase 1: all B frags + A frags mi 0,1 -> 16 MFMA ----
    bf16x8 bfr[4][2], afA[2][2];
#pragma unroll
    for (int ni = 0; ni < 4; ++ni)
#pragma unroll
      for (int kk = 0; kk < 2; ++kk) {
        const int r = wn * 64 + ni * 16 + frow;
        const int g = ((kk << 2) + hi) ^ (frow & 7);
        bfr[ni][kk] = *(const bf16x8*)&B_[r * 64 + g * 8];
      }
#pragma unroll
    for (int mi = 0; mi < 2; ++mi)
#pragma unroll
      for (int kk = 0; kk < 2; ++kk) {
        const int r = wm * 64 + mi * 16 + frow;
        const int g = ((kk << 2) + hi) ^ (frow & 7);
        afA[mi][kk] = *(const bf16x8*)&A_[r * 64 + g * 8];
      }
    WAITL0;
    __builtin_amdgcn_s_setprio(1);
#pragma unroll
    for (int mi = 0; mi < 2; ++mi)
#pragma unroll
      for (int ni = 0; ni < 4; ++ni)
#pragma unroll
        for (int kk = 0; kk < 2; ++kk)
          acc_e[mi][ni] = __builtin_amdgcn_mfma_f32_16x16x32_bf16(
              afA[mi][kk], bfr[ni][kk], acc_e[mi][ni], 0, 0, 0);
    __builtin_amdgcn_s_setprio(0);

    // ---- phase 2: A frags mi 2,3 -> 16 MFMA ----
    bf16x8 afB[2][2];
#pragma unroll
    for (int mi = 0; mi < 2; ++mi)
#pragma unroll
      for (int kk = 0; kk < 2; ++kk) {
        const int r = wm * 64 + (mi + 2) * 16 + frow;
        const int g = ((kk << 2) + hi) ^ (frow & 7);
        afB[mi][kk] = *(const bf16x8*)&A_[r * 64 + g * 8];
      }
    WAITL0;
    __builtin_amdgcn_s_setprio(1);
#pragma unroll
    for (int mi = 0; mi < 2; ++mi)
#pragma unroll
      for (int ni = 0; ni < 4; ++ni)
#pragma unroll
        for (int kk = 0; kk < 2; ++kk)
          acc_e[mi + 2][ni] = __builtin_amdgcn_mfma_f32_16x16x32_bf16(
              afB[mi][kk], bfr[ni][kk], acc_e[mi + 2][ni], 0, 0, 0);
    __builtin_amdgcn_s_setprio(0);

    // ---- expert boundary: fold acc_e into acc scaled by g ----
    if ((kt & 15) == 15) {
      const int e = kt >> 4;
#pragma unroll
      for (int mi = 0; mi < 4; ++mi) {
        float4 gv = *(const float4*)&g_lds[e][wm * 64 + mi * 16 + hi * 4];
        f32x4 g4 = f32x4{gv.x, gv.y, gv.z, gv.w};
#pragma unroll
        for (int ni = 0; ni < 4; ++ni) {
          acc[mi][ni] += g4 * acc_e[mi][ni];
          acc_e[mi][ni] = f32x4{0.f, 0.f, 0.f, 0.f};
        }
      }
    }
    if (++cur == 3) cur = 0;
  }

  // split-K contribution via atomics (out pre-zeroed)
  const int orow0 = row0 + wm * 64 + hi * 4;
  const int ocol0 = col0 + wn * 64 + frow;
#pragma unroll
  for (int mi = 0; mi < 4; ++mi)
#pragma unroll
    for (int j = 0; j < 4; ++j) {
      const int r = orow0 + mi * 16 + j;
#pragma unroll
      for (int ni = 0; ni < 4; ++ni)
        atomicAdd(out + (size_t)r * ODIM + ocol0 + ni * 16, acc[mi][ni][j]);
    }
}

extern "C" void kernel_launch(void* const* d_in, const int* in_sizes, int n_in,
                              void* d_out, int out_size, void* d_ws, size_t ws_size,
                              hipStream_t stream) {
  const float* x  = (const float*)d_in[0];   // [4096][1024]
  const float* w  = (const float*)d_in[1];   // [32][1024][1024]
  const float* gw = (const float*)d_in[2];   // [32][1024]
  const float* gb = (const float*)d_in[3];   // [32]
  float* out = (float*)d_out;                // [4096][1024]

  unsigned short* xb   = (unsigned short*)d_ws;                          // 8 MB
  unsigned short* wbuf = (unsigned short*)((char*)d_ws + (8u << 20));    // 64 MB
  float*          gT   = (float*)((char*)d_ws + (72u << 20));            // 512 KB

  zero_kernel<<<(BSZ * ODIM / 4) / 256, 256, 0, stream>>>(out);
  conv_kernel<<<(BSZ * IDIM / 8) / 256, 256, 0, stream>>>(x, xb);
  conv_kernel<<<(NEXP * ODIM * IDIM / 8) / 256, 256, 0, stream>>>(w, wbuf);
  gate_kernel<<<BSZ / 4, 256, 0, stream>>>(x, gw, gb, gT);

  gemm_kernel<<<256, 512, 0, stream>>>(xb, wbuf, gT, out);
}

// Round 4
// 347.628 us; speedup vs baseline: 1.2073x; 1.2073x over previous
//
#include <hip/hip_runtime.h>
#include <hip/hip_bf16.h>
#include <math.h>

// MOE: out[b,o] = sum_n gelu(x@gw^T+gb)[b,n] * (x @ W_n^T)[b,o]
// B=4096, N=32, IDIM=ODIM=1024.
// R4: m201-style lockstep phase schedule. BM=256 BN=128 BK=64, 8 waves
// (4Mx2N, wave 64x64), K-tile = 2 phases split by K-halves (8 ds_read + 16
// MFMA each), 2 barriers/phase, counted vmcnt(6) once per K-tile, triple
// buffer distance-2 prefetch, setprio around MFMA clusters. Per-expert fold
// into dual accumulator; split-K x2 via fp32 atomics.

#define BSZ  4096
#define NEXP 32
#define IDIM 1024
#define ODIM 1024

typedef __attribute__((ext_vector_type(8))) short bf16x8;
typedef __attribute__((ext_vector_type(4))) float f32x4;

#define GLOAD_LDS16(g, l) __builtin_amdgcn_global_load_lds( \
    (const __attribute__((address_space(1))) void*)(g),     \
    (__attribute__((address_space(3))) void*)(l), 16, 0, 0)

#define SBAR __builtin_amdgcn_sched_barrier(0)
#define WAITV6 do { asm volatile("s_waitcnt vmcnt(6)" ::: "memory"); SBAR; } while (0)
#define WAITV0 do { asm volatile("s_waitcnt vmcnt(0)" ::: "memory"); SBAR; } while (0)
#define WAITL0 do { asm volatile("s_waitcnt lgkmcnt(0)" ::: "memory"); SBAR; } while (0)
#define BARRIER do { __builtin_amdgcn_s_barrier(); SBAR; } while (0)

__device__ __forceinline__ unsigned short f2bf(float f) {
  unsigned u = __float_as_uint(f);
  unsigned r = (u + 0x7FFFu + ((u >> 16) & 1u)) >> 16;  // RNE
  return (unsigned short)r;
}

// ---------------- zero d_out ----------------
__global__ void zero_kernel(float* __restrict__ out) {
  int i = blockIdx.x * blockDim.x + threadIdx.x;
  ((float4*)out)[i] = make_float4(0.f, 0.f, 0.f, 0.f);
}

// ---------------- fp32 -> bf16 conversion (8 elems/thread) ----------------
__global__ void conv_kernel(const float* __restrict__ in, unsigned short* __restrict__ outb) {
  int i = blockIdx.x * blockDim.x + threadIdx.x;
  const float4* p = (const float4*)in + (size_t)i * 2;
  float4 a = p[0], b = p[1];
  union { bf16x8 v; unsigned short s[8]; } o;
  o.s[0] = f2bf(a.x); o.s[1] = f2bf(a.y); o.s[2] = f2bf(a.z); o.s[3] = f2bf(a.w);
  o.s[4] = f2bf(b.x); o.s[5] = f2bf(b.y); o.s[6] = f2bf(b.z); o.s[7] = f2bf(b.w);
  ((bf16x8*)outb)[i] = o.v;
}

// ---------------- gate: gT[n][b] = gelu(x[b]·gw[n] + gb[n]) ----------------
__global__ void gate_kernel(const float* __restrict__ x, const float* __restrict__ gw,
                            const float* __restrict__ gb, float* __restrict__ gT) {
  const int lane = threadIdx.x & 63;
  const int row = blockIdx.x * 4 + (threadIdx.x >> 6);
  const float4* xr = (const float4*)(x + (size_t)row * IDIM);
  float4 xv[4];
#pragma unroll
  for (int t = 0; t < 4; ++t) xv[t] = xr[t * 64 + lane];
  for (int n = 0; n < NEXP; ++n) {
    const float4* wr = (const float4*)(gw + (size_t)n * IDIM);
    float s = 0.f;
#pragma unroll
    for (int t = 0; t < 4; ++t) {
      float4 wv = wr[t * 64 + lane];
      s += xv[t].x * wv.x + xv[t].y * wv.y + xv[t].z * wv.z + xv[t].w * wv.w;
    }
#pragma unroll
    for (int off = 32; off > 0; off >>= 1) s += __shfl_down(s, off, 64);
    if (lane == 0) {
      float v = s + gb[n];
      gT[(size_t)n * BSZ + row] = 0.5f * v * (1.0f + erff(v * 0.70710678118f));
    }
  }
}

// ---------------- main GEMM ----------------
__global__ __launch_bounds__(512, 2) void gemm_kernel(
    const unsigned short* __restrict__ xb,   // [4096][1024] bf16
    const unsigned short* __restrict__ wb,   // [32][1024][1024] bf16 (n,o,i)
    const float* __restrict__ gT,            // [32][4096]
    float* __restrict__ out)                 // [4096][1024] fp32
{
  __shared__ unsigned short As[3][256 * 64];   // 96 KB
  __shared__ unsigned short Bs[3][128 * 64];   // 48 KB
  __shared__ float g_lds[16][256];             // 16 KB  (160 KiB total)

  const int tid  = threadIdx.x;
  const int lane = tid & 63;
  const int wid  = tid >> 6;     // 0..7
  const int wm   = wid >> 1;     // 0..3 (M)
  const int wn   = wid & 1;      // 0..1 (N)

  // XCD-chunked block swizzle (256 % 8 == 0 -> bijective)
  const int orig  = blockIdx.x;
  const int wgid  = (orig & 7) * 32 + (orig >> 3);
  const int mtile = wgid & 15;          // innermost: 16 blocks share W panel
  const int grp   = wgid >> 4;
  const int split = grp & 1;
  const int col0  = (grp >> 1) * 128;
  const int row0  = mtile * 256;

  // staging: lane -> (row-in-chunk, pre-swizzled source granule)
  const int srow = lane >> 3;
  const int jsrc = (lane & 7) ^ srow;
  size_t a_off[4], b_off[2];
#pragma unroll
  for (int l = 0; l < 4; ++l)
    a_off[l] = (size_t)(row0 + (wid * 4 + l) * 8 + srow) * IDIM + jsrc * 8;
#pragma unroll
  for (int l = 0; l < 2; ++l)
    b_off[l] = (size_t)(col0 + (wid * 2 + l) * 8 + srow) * IDIM + jsrc * 8;

  const int frow = lane & 15;
  const int hi   = lane >> 4;

  f32x4 acc[4][4], acc_e[4][4];
#pragma unroll
  for (int i = 0; i < 4; ++i)
#pragma unroll
    for (int j = 0; j < 4; ++j) {
      acc[i][j]   = f32x4{0.f, 0.f, 0.f, 0.f};
      acc_e[i][j] = f32x4{0.f, 0.f, 0.f, 0.f};
    }

  // gate slice -> LDS (16 experts x 256 rows)
  {
    const int e = tid >> 5;
    const int r = (tid & 31) * 8;
    const float* src = gT + ((size_t)(split * 16 + e) << 12) + row0 + r;
    *(float4*)&g_lds[e][r]     = *(const float4*)src;
    *(float4*)&g_lds[e][r + 4] = *(const float4*)(src + 4);
  }

  // stage half: 3 loads (2 A chunks + 1 B chunk)
  auto STAGE_H = [&](int buf, int kt, int half) {
    const int e  = kt >> 4;
    const int i0 = (kt & 15) << 6;
    const unsigned short* wb_n = wb + ((size_t)(split * 16 + e) << 20);
#pragma unroll
    for (int l = half * 2; l < half * 2 + 2; ++l)
      GLOAD_LDS16(xb + a_off[l] + i0, &As[buf][(wid * 4 + l) * 512]);
    GLOAD_LDS16(wb_n + b_off[half] + i0, &Bs[buf][(wid * 2 + half) * 512]);
  };

  __syncthreads();            // g_lds visible; prologue-only full drain
  STAGE_H(0, 0, 0); STAGE_H(0, 0, 1);   // tile 0: 6 loads
  STAGE_H(1, 1, 0); STAGE_H(1, 1, 1);   // tile 1: 12 outstanding
  WAITV6;                     // tile 0 resident (this wave)
  BARRIER;                    // tile 0 resident (all waves)

  int cur = 0;
#pragma unroll 1
  for (int kt = 0; kt < 256; ++kt) {
    int sbuf = cur + 2; if (sbuf >= 3) sbuf -= 3;   // buffer freed at kt-1 end
    const unsigned short* A_ = &As[cur][0];
    const unsigned short* B_ = &Bs[cur][0];
    const int g0 = hi ^ (frow & 7);        // granule, kk=0
    const int g1 = (4 + hi) ^ (frow & 7);  // granule, kk=1

    // ======== phase A (kk = 0) ========
    bf16x8 af0[4], bf0[4];
#pragma unroll
    for (int ni = 0; ni < 4; ++ni)
      bf0[ni] = *(const bf16x8*)&B_[(wn * 64 + ni * 16 + frow) * 64 + g0 * 8];
#pragma unroll
    for (int mi = 0; mi < 4; ++mi)
      af0[mi] = *(const bf16x8*)&A_[(wm * 64 + mi * 16 + frow) * 64 + g0 * 8];
    if (kt < 254) STAGE_H(sbuf, kt + 2, 0);
    BARRIER;
    WAITL0;
    __builtin_amdgcn_s_setprio(1);
#pragma unroll
    for (int mi = 0; mi < 4; ++mi)
#pragma unroll
      for (int ni = 0; ni < 4; ++ni)
        acc_e[mi][ni] = __builtin_amdgcn_mfma_f32_16x16x32_bf16(
            af0[mi], bf0[ni], acc_e[mi][ni], 0, 0, 0);
    __builtin_amdgcn_s_setprio(0);
    BARRIER;

    // ======== phase B (kk = 1) ========
    bf16x8 af1[4], bf1[4];
#pragma unroll
    for (int ni = 0; ni < 4; ++ni)
      bf1[ni] = *(const bf16x8*)&B_[(wn * 64 + ni * 16 + frow) * 64 + g1 * 8];
#pragma unroll
    for (int mi = 0; mi < 4; ++mi)
      af1[mi] = *(const bf16x8*)&A_[(wm * 64 + mi * 16 + frow) * 64 + g1 * 8];
    if (kt < 254) STAGE_H(sbuf, kt + 2, 1);
    // counted vmcnt: prove tile kt+1 resident before any wave reads it
    if (kt < 254) { WAITV6; } else if (kt == 254) { WAITV0; }
    BARRIER;
    WAITL0;
    __builtin_amdgcn_s_setprio(1);
#pragma unroll
    for (int mi = 0; mi < 4; ++mi)
#pragma unroll
      for (int ni = 0; ni < 4; ++ni)
        acc_e[mi][ni] = __builtin_amdgcn_mfma_f32_16x16x32_bf16(
            af1[mi], bf1[ni], acc_e[mi][ni], 0, 0, 0);
    __builtin_amdgcn_s_setprio(0);

    // expert boundary: fold acc_e into acc scaled by g
    if ((kt & 15) == 15) {
      const int e = kt >> 4;
#pragma unroll
      for (int mi = 0; mi < 4; ++mi) {
        float4 gv = *(const float4*)&g_lds[e][wm * 64 + mi * 16 + hi * 4];
        f32x4 g4 = f32x4{gv.x, gv.y, gv.z, gv.w};
#pragma unroll
        for (int ni = 0; ni < 4; ++ni) {
          acc[mi][ni] += g4 * acc_e[mi][ni];
          acc_e[mi][ni] = f32x4{0.f, 0.f, 0.f, 0.f};
        }
      }
    }
    BARRIER;
    if (++cur == 3) cur = 0;
  }

  // split-K contribution via atomics (out pre-zeroed)
  const int orow0 = row0 + wm * 64 + hi * 4;
  const int ocol0 = col0 + wn * 64 + frow;
#pragma unroll
  for (int mi = 0; mi < 4; ++mi)
#pragma unroll
    for (int j = 0; j < 4; ++j) {
      const int r = orow0 + mi * 16 + j;
#pragma unroll
      for (int ni = 0; ni < 4; ++ni)
        atomicAdd(out + (size_t)r * ODIM + ocol0 + ni * 16, acc[mi][ni][j]);
    }
}

extern "C" void kernel_launch(void* const* d_in, const int* in_sizes, int n_in,
                              void* d_out, int out_size, void* d_ws, size_t ws_size,
                              hipStream_t stream) {
  const float* x  = (const float*)d_in[0];   // [4096][1024]
  const float* w  = (const float*)d_in[1];   // [32][1024][1024]
  const float* gw = (const float*)d_in[2];   // [32][1024]
  const float* gb = (const float*)d_in[3];   // [32]
  float* out = (float*)d_out;                // [4096][1024]

  unsigned short* xb   = (unsigned short*)d_ws;                          // 8 MB
  unsigned short* wbuf = (unsigned short*)((char*)d_ws + (8u << 20));    // 64 MB
  float*          gT   = (float*)((char*)d_ws + (72u << 20));            // 512 KB

  zero_kernel<<<(BSZ * ODIM / 4) / 256, 256, 0, stream>>>(out);
  conv_kernel<<<(BSZ * IDIM / 8) / 256, 256, 0, stream>>>(x, xb);
  conv_kernel<<<(NEXP * ODIM * IDIM / 8) / 256, 256, 0, stream>>>(w, wbuf);
  gate_kernel<<<BSZ / 4, 256, 0, stream>>>(x, gw, gb, gT);

  gemm_kernel<<<256, 512, 0, stream>>>(xb, wbuf, gT, out);
}